// Round 6
// baseline (1237.732 us; speedup 1.0000x reference)
//
#include <hip/hip_runtime.h>
#include <hip/hip_bf16.h>
#include <cmath>

// Problem constants
#define B_    4
#define T_    2048
#define DIM_  1024
#define H_    16
#define NOPE_ 128
#define ROPE_ 64
#define VDIM_ 128
#define KVR_  512
#define QKD_  192          // NOPE + ROPE
#define NTOK  (B_ * T_)    // 8192

static constexpr float SCALE_ = 0.07216878364870322f;  // 1/sqrt(192)

typedef __attribute__((ext_vector_type(8))) unsigned short ushort8_t;
typedef __bf16 v8bf __attribute__((ext_vector_type(8)));
typedef float  v4f  __attribute__((ext_vector_type(4)));

__device__ __forceinline__ float bf2f(unsigned short u) {
    return __uint_as_float(((unsigned int)u) << 16);
}
// round-to-nearest-even f32 -> bf16 bits (finite inputs)
__device__ __forceinline__ unsigned short f2bf(float f) {
    unsigned int u = __float_as_uint(f);
    u += 0x7FFFu + ((u >> 16) & 1u);
    return (unsigned short)(u >> 16);
}
__device__ __forceinline__ void store1(float* p, float v)          { *p = v; }
__device__ __forceinline__ void store1(__hip_bfloat16* p, float v) { *p = __float2bfloat16(v); }

// async global->LDS, 16B per lane. LDS dest = wave-uniform base + lane*16.
__device__ __forceinline__ void load_lds16(const void* g, void* l) {
    __builtin_amdgcn_global_load_lds(
        (const __attribute__((address_space(1))) void*)g,
        (__attribute__((address_space(3))) void*)l, 16, 0, 0);
}

// ---------------------------------------------------------------------------
// fp32 -> bf16 conversion (n % 4 == 0)
// ---------------------------------------------------------------------------
__global__ __launch_bounds__(256) void cvt_bf16(
    const float* __restrict__ s, __hip_bfloat16* __restrict__ d, int n)
{
    const int i = (blockIdx.x * 256 + threadIdx.x) * 4;
    if (i < n) {
        const float4 v = *(const float4*)(s + i);
        ushort4 o;
        o.x = f2bf(v.x); o.y = f2bf(v.y); o.z = f2bf(v.z); o.w = f2bf(v.w);
        *(ushort4*)((unsigned short*)d + i) = o;
    }
}

// wkv_a: (576,1024) fp32 -> (640,1024) bf16 zero-padded; bias 576 -> 640 fp32
__global__ __launch_bounds__(256) void cvt_pad_kva(
    const float* __restrict__ w, const float* __restrict__ b,
    __hip_bfloat16* __restrict__ wd, float* __restrict__ bd)
{
    const int gid = blockIdx.x * 256 + threadIdx.x;
    const int i = gid * 4;                     // over 640*1024
    if (i < 640 * 1024) {
        ushort4 o;
        if (i < 576 * 1024) {
            const float4 v = *(const float4*)(w + i);
            o.x = f2bf(v.x); o.y = f2bf(v.y); o.z = f2bf(v.z); o.w = f2bf(v.w);
        } else {
            o.x = o.y = o.z = o.w = 0;
        }
        *(ushort4*)((unsigned short*)wd + i) = o;
    }
    if (gid < 640) bd[gid] = (gid < 576) ? b[gid] : 0.0f;
}

// ---------------------------------------------------------------------------
// MFMA GEMM: C[m][n] = sum_k A[m][k]*W[n][k] + bias[n]. A,W bf16, acc fp32.
// Tiles 128x128xBK32, 4 waves (2x2 of 64x64), 16x16x32 MFMA.
// EPI=0: plain store to C. EPI=1: kv_b split epilogue (kn + vt transposed).
// ---------------------------------------------------------------------------
template <typename CT, int EPI>
__global__ __launch_bounds__(256) void gemm_mfma(
    const __hip_bfloat16* __restrict__ A, int lda,
    const __hip_bfloat16* __restrict__ W, int ldw,
    const float* __restrict__ bias,
    CT* __restrict__ C, int ldc, int K,
    __hip_bfloat16* __restrict__ vt)
{
    __shared__ unsigned short A_s[128 * 32];
    __shared__ unsigned short B_s[128 * 32];

    const int tid  = threadIdx.x;
    const int ln   = tid & 63;
    const int wv   = tid >> 6;
    const int l15  = ln & 15;
    const int quad = ln >> 4;
    const int wm   = wv & 1, wn = wv >> 1;
    const int n0 = blockIdx.x * 128, m0 = blockIdx.y * 128;

    v4f acc[4][4] = {};

    for (int k0 = 0; k0 < K; k0 += 32) {
        __syncthreads();
        #pragma unroll
        for (int it = 0; it < 2; ++it) {
            const int idx = it * 256 + wv * 64;   // wave-uniform LDS slot base
            const int li  = idx + ln;
            const int row = li >> 2, ch = li & 3;
            load_lds16(A + (size_t)(m0 + row) * lda + k0 + ch * 8, &A_s[idx * 8]);
            load_lds16(W + (size_t)(n0 + row) * ldw + k0 + ch * 8, &B_s[idx * 8]);
        }
        __syncthreads();

        v8bf af[4], bf_[4];
        #pragma unroll
        for (int i = 0; i < 4; ++i) {
            af[i]  = *(const v8bf*)&A_s[(wm * 64 + i * 16 + l15) * 32 + quad * 8];
            bf_[i] = *(const v8bf*)&B_s[(wn * 64 + i * 16 + l15) * 32 + quad * 8];
        }
        #pragma unroll
        for (int i = 0; i < 4; ++i)
            #pragma unroll
            for (int j = 0; j < 4; ++j)
                acc[i][j] = __builtin_amdgcn_mfma_f32_16x16x32_bf16(
                                af[i], bf_[j], acc[i][j], 0, 0, 0);
    }

    if (EPI == 0) {
        #pragma unroll
        for (int i = 0; i < 4; ++i) {
            const int mrow = m0 + wm * 64 + i * 16 + quad * 4;
            #pragma unroll
            for (int j = 0; j < 4; ++j) {
                const int ncol = n0 + wn * 64 + j * 16 + l15;
                const float bb = bias[ncol];
                #pragma unroll
                for (int r = 0; r < 4; ++r)
                    store1(C + (size_t)(mrow + r) * ldc + ncol, acc[i][j][r] + bb);
            }
        }
    } else {
        const int head = n0 >> 8;
        const bool is_v = (n0 & 128) != 0;
        #pragma unroll
        for (int i = 0; i < 4; ++i) {
            const int mrow = m0 + wm * 64 + i * 16 + quad * 4;
            #pragma unroll
            for (int j = 0; j < 4; ++j) {
                const int ncl = wn * 64 + j * 16 + l15;
                const float bb = bias[n0 + ncl];
                if (!is_v) {
                    __hip_bfloat16* kn = (__hip_bfloat16*)C;
                    #pragma unroll
                    for (int r = 0; r < 4; ++r)
                        kn[(size_t)(mrow + r) * 2048 + head * 128 + ncl] =
                            __float2bfloat16(acc[i][j][r] + bb);
                } else {
                    ushort4 pk;
                    pk.x = f2bf(acc[i][j][0] + bb);
                    pk.y = f2bf(acc[i][j][1] + bb);
                    pk.z = f2bf(acc[i][j][2] + bb);
                    pk.w = f2bf(acc[i][j][3] + bb);
                    *(ushort4*)((unsigned short*)vt +
                                ((size_t)head * 128 + ncl) * NTOK + mrow) = pk;
                }
            }
        }
    }
}

// ---------------------------------------------------------------------------
// RoPE on q's last 64 dims of each head. q: (NTOK, H*QKD) bf16.
// ---------------------------------------------------------------------------
__global__ __launch_bounds__(512) void rope_q(
    __hip_bfloat16* __restrict__ q,
    const float* __restrict__ cs,   // (T, 32)
    const float* __restrict__ sn)
{
    const int tok = blockIdx.x;
    const int tid = threadIdx.x;
    const int h = tid >> 5;
    const int i = tid & 31;
    const int t = tok & (T_ - 1);

    const float c = cs[t*32 + i];
    const float s = sn[t*32 + i];
    __hip_bfloat16* p = q + (size_t)tok * (H_*QKD_) + h*QKD_ + NOPE_ + 2*i;
    const float xr = __bfloat162float(p[0]);
    const float xi = __bfloat162float(p[1]);
    p[0] = __float2bfloat16(xr * c - xi * s);
    p[1] = __float2bfloat16(xr * s + xi * c);
}

// ---------------------------------------------------------------------------
// RMS-norm kv_a[:,0:512] -> kvn bf16; RoPE kv_a[:,512:576] -> kr bf16.
// ---------------------------------------------------------------------------
__global__ __launch_bounds__(256) void rmsnorm_ropek(
    const __hip_bfloat16* __restrict__ kva,
    __hip_bfloat16* __restrict__ kvn,
    __hip_bfloat16* __restrict__ kr,
    const float* __restrict__ cs,
    const float* __restrict__ sn)
{
    const int tok = blockIdx.x;
    const int tid = threadIdx.x;
    const __hip_bfloat16* row = kva + (size_t)tok * 640;

    const float x0 = __bfloat162float(row[tid]);
    const float x1 = __bfloat162float(row[tid + 256]);
    float ss = x0*x0 + x1*x1;
    #pragma unroll
    for (int off = 32; off >= 1; off >>= 1)
        ss += __shfl_down(ss, off);

    __shared__ float red[4];
    __shared__ float scale_sh;
    if ((tid & 63) == 0) red[tid >> 6] = ss;
    __syncthreads();
    if (tid == 0) {
        const float tot = red[0] + red[1] + red[2] + red[3];
        scale_sh = rsqrtf(tot * (1.0f/512.0f) + 1e-6f);
    }
    __syncthreads();
    const float sc = scale_sh;
    kvn[(size_t)tok*512 + tid]       = __float2bfloat16(x0 * sc);
    kvn[(size_t)tok*512 + tid + 256] = __float2bfloat16(x1 * sc);

    if (tid < 32) {
        const int t = tok & (T_ - 1);
        const float c = cs[t*32 + tid];
        const float s = sn[t*32 + tid];
        const float xr = __bfloat162float(row[KVR_ + 2*tid]);
        const float xi = __bfloat162float(row[KVR_ + 2*tid + 1]);
        kr[(size_t)tok*64 + 2*tid]     = __float2bfloat16(xr * c - xi * s);
        kr[(size_t)tok*64 + 2*tid + 1] = __float2bfloat16(xr * s + xi * c);
    }
}

// ---------------------------------------------------------------------------
// Barrier-free MFMA flash attention. One WAVE (64 threads) per block; wave
// owns 16 q-rows, iterates BK=64 k-tiles. K/V fragments are loaded DIRECTLY
// from global (L2-resident per (b,h): kn+kr+vt ~1.3 MB); no staging LDS, no
// __syncthreads. Only LDS use: 2.3 KB wave-private P transpose buffer
// (C-layout -> A-layout; same-wave write->read, HW-validated in r3/r5).
//   q  : (NTOK, 3072) bf16, head h at h*192, RoPE'd. Pre-scaled on load.
//   kn : (NTOK, 2048) bf16, head h k_nope at h*128.
//   kr : (NTOK, 64) bf16, shared rope'd k.
//   vt : (H,128,NTOK) bf16, V pre-transposed.
//   att: (NTOK, 2048) bf16, head h at h*128.
// __launch_bounds__(64,4): cap 128 VGPR -> 4 waves/SIMD for latency hiding.
// ---------------------------------------------------------------------------
__global__ __launch_bounds__(64, 4) void attn_mfma(
    const __hip_bfloat16* __restrict__ q,
    const __hip_bfloat16* __restrict__ kn,
    const __hip_bfloat16* __restrict__ kr,
    const __hip_bfloat16* __restrict__ vt,
    __hip_bfloat16* __restrict__ att)
{
    __shared__ unsigned short P_s[16][72];   // wave-private, pad 64->72

    const int tid  = threadIdx.x;
    const int ln   = tid & 15;
    const int quad = tid >> 4;              // 0..3

    const int qt = (int)(gridDim.x - 1) - (int)blockIdx.x;  // longest first
    const int h  = blockIdx.y, b = blockIdx.z;
    const int q0 = qt * 16;
    const size_t tokb = (size_t)b * T_;

    // Q fragments (A layout), pre-scaled
    v8bf qf[6];
    {
        const __hip_bfloat16* qrow =
            q + (tokb + q0 + ln) * (size_t)(H_*QKD_) + h*QKD_;
        #pragma unroll
        for (int s = 0; s < 6; ++s) {
            ushort8_t raw = *(const ushort8_t*)(qrow + s*32 + quad*8);
            ushort8_t sc;
            #pragma unroll
            for (int i = 0; i < 8; ++i)
                sc[i] = f2bf(bf2f(raw[i]) * SCALE_);
            qf[s] = __builtin_bit_cast(v8bf, sc);
        }
    }

    v4f O[8];
    #pragma unroll
    for (int nt = 0; nt < 8; ++nt) O[nt] = (v4f){0.f, 0.f, 0.f, 0.f};
    float m_r[4], l_r[4];
    #pragma unroll
    for (int r = 0; r < 4; ++r) { m_r[r] = -1e30f; l_r[r] = 0.0f; }

    const __hip_bfloat16* vth = vt + (size_t)h * 128 * NTOK;

    const int nkt = (q0 + 16 + 63) >> 6;
    for (int kt = 0; kt < nkt; ++kt) {
        const int j0 = kt * 64;

        // ---- S = Q K^T: B-fragments straight from global (L2) ----
        v4f S[4];
        #pragma unroll
        for (int t = 0; t < 4; ++t) S[t] = (v4f){0.f, 0.f, 0.f, 0.f};
        #pragma unroll
        for (int s = 0; s < 6; ++s) {
            v8bf kb[4];
            #pragma unroll
            for (int t = 0; t < 4; ++t) {
                const size_t row = tokb + j0 + t*16 + ln;
                kb[t] = (s < 4)
                    ? *(const v8bf*)(kn + row*2048 + h*128 + s*32 + quad*8)
                    : *(const v8bf*)(kr + row*64 + (s-4)*32 + quad*8);
            }
            #pragma unroll
            for (int t = 0; t < 4; ++t)
                S[t] = __builtin_amdgcn_mfma_f32_16x16x32_bf16(qf[s], kb[t], S[t], 0, 0, 0);
        }

        // ---- causal mask on the diagonal tile ----
        if (kt == nkt - 1) {
            #pragma unroll
            for (int t = 0; t < 4; ++t) {
                const int kpos = j0 + t*16 + ln;
                #pragma unroll
                for (int r = 0; r < 4; ++r) {
                    const int qpos = q0 + quad*4 + r;
                    if (kpos > qpos) S[t][r] = -1e30f;
                }
            }
        }

        // ---- online softmax (reduce across 16-lane row groups) ----
        float alpha[4];
        #pragma unroll
        for (int r = 0; r < 4; ++r) {
            float mx = fmaxf(fmaxf(S[0][r], S[1][r]), fmaxf(S[2][r], S[3][r]));
            #pragma unroll
            for (int off = 1; off < 16; off <<= 1)
                mx = fmaxf(mx, __shfl_xor(mx, off));
            const float mn = fmaxf(m_r[r], mx);
            alpha[r] = __expf(m_r[r] - mn);
            m_r[r] = mn;
        }
        float rs[4] = {0.f, 0.f, 0.f, 0.f};
        #pragma unroll
        for (int t = 0; t < 4; ++t)
            #pragma unroll
            for (int r = 0; r < 4; ++r) {
                const float p = __expf(S[t][r] - m_r[r]);
                S[t][r] = p;
                rs[r] += p;
            }
        #pragma unroll
        for (int r = 0; r < 4; ++r) {
            #pragma unroll
            for (int off = 1; off < 16; off <<= 1)
                rs[r] += __shfl_xor(rs[r], off);
            l_r[r] = l_r[r]*alpha[r] + rs[r];
        }

        // ---- P: C layout -> LDS -> A layout (same wave) ----
        #pragma unroll
        for (int t = 0; t < 4; ++t)
            #pragma unroll
            for (int r = 0; r < 4; ++r)
                P_s[quad*4 + r][t*16 + ln] = f2bf(S[t][r]);

        #pragma unroll
        for (int nt = 0; nt < 8; ++nt)
            #pragma unroll
            for (int r = 0; r < 4; ++r)
                O[nt][r] *= alpha[r];

        // ---- O += P V: V^T fragments straight from global (L2) ----
        #pragma unroll
        for (int s2 = 0; s2 < 2; ++s2) {
            const v8bf pa = *(const v8bf*)&P_s[ln][s2*32 + quad*8];
            v8bf vb[8];
            #pragma unroll
            for (int nt = 0; nt < 8; ++nt)
                vb[nt] = *(const v8bf*)(vth + (size_t)(nt*16 + ln)*NTOK
                                        + tokb + j0 + s2*32 + quad*8);
            #pragma unroll
            for (int nt = 0; nt < 8; ++nt)
                O[nt] = __builtin_amdgcn_mfma_f32_16x16x32_bf16(pa, vb[nt], O[nt], 0, 0, 0);
        }
    }

    // ---- epilogue ----
    __hip_bfloat16* obase = att + (tokb + q0) * (size_t)(H_*VDIM_) + h*VDIM_;
    #pragma unroll
    for (int r = 0; r < 4; ++r) {
        const float inv = 1.0f / l_r[r];
        __hip_bfloat16* orow = obase + (size_t)(quad*4 + r) * (H_*VDIM_);
        #pragma unroll
        for (int nt = 0; nt < 8; ++nt)
            orow[nt*16 + ln] = __float2bfloat16(O[nt][r] * inv);
    }
}

// Diagnostic fallback
__global__ void fill_zero(float* p, int n) {
    int i = blockIdx.x * 256 + threadIdx.x;
    if (i < n) p[i] = 0.0f;
}

// ---------------------------------------------------------------------------
extern "C" void kernel_launch(void* const* d_in, const int* in_sizes, int n_in,
                              void* d_out, int out_size, void* d_ws, size_t ws_size,
                              hipStream_t stream)
{
    const float* x      = (const float*)d_in[0];
    const float* wq_w   = (const float*)d_in[1];
    const float* wq_b   = (const float*)d_in[2];
    const float* wkva_w = (const float*)d_in[3];
    const float* wkva_b = (const float*)d_in[4];
    const float* wkvb_w = (const float*)d_in[5];
    const float* wkvb_b = (const float*)d_in[6];
    const float* wo_w   = (const float*)d_in[7];
    const float* wo_b   = (const float*)d_in[8];
    const float* cs     = (const float*)d_in[9];
    const float* sn     = (const float*)d_in[10];

    const size_t q_b    = (size_t)NTOK * 3072 * 2;
    const size_t kn_b   = (size_t)NTOK * 2048 * 2;
    const size_t vt_b   = (size_t)H_ * 128 * NTOK * 2;
    const size_t xb_b   = (size_t)NTOK * 1024 * 2;
    const size_t kvap_b = (size_t)NTOK * 640 * 2;
    const size_t kvn_b  = (size_t)NTOK * 512 * 2;
    const size_t wq_b_b = (size_t)3072 * 1024 * 2;
    const size_t wkva_b_b = (size_t)640 * 1024 * 2;
    const size_t wkvb_b_b = (size_t)4096 * 512 * 2;
    const size_t wo_b_b   = (size_t)1024 * 2048 * 2;
    const size_t bias_b   = 4096;
    const size_t need = q_b + kn_b + vt_b + xb_b + kvap_b + kvn_b +
                        wq_b_b + wkva_b_b + wkvb_b_b + wo_b_b + bias_b;

    if (ws_size < need) {
        fill_zero<<<(out_size + 255) / 256, 256, 0, stream>>>((float*)d_out, out_size);
        return;
    }

    char* p = (char*)d_ws;
    __hip_bfloat16* q    = (__hip_bfloat16*)p;             p += q_b;
    __hip_bfloat16* kn   = (__hip_bfloat16*)p;             p += kn_b;
    __hip_bfloat16* vt   = (__hip_bfloat16*)p;             p += vt_b;
    char*           dynr = p;
    __hip_bfloat16* xb   = (__hip_bfloat16*)p;             p += xb_b;
    __hip_bfloat16* kvap = (__hip_bfloat16*)p;             p += kvap_b;
    __hip_bfloat16* kvn  = (__hip_bfloat16*)p;             p += kvn_b;
    __hip_bfloat16* wq_bf = (__hip_bfloat16*)p;
    __hip_bfloat16* kr    = (__hip_bfloat16*)p;            p += wq_b_b;
    __hip_bfloat16* wkva_bf = (__hip_bfloat16*)p;          p += wkva_b_b;
    __hip_bfloat16* wkvb_bf = (__hip_bfloat16*)p;          p += wkvb_b_b;
    __hip_bfloat16* wo_bf   = (__hip_bfloat16*)p;          p += wo_b_b;
    float*          bias_pad = (float*)p;
    __hip_bfloat16* attb = (__hip_bfloat16*)dynr;
    float*          out  = (float*)d_out;

    // 1) conversions
    cvt_bf16<<<NTOK*1024/4/256, 256, 0, stream>>>(x, xb, NTOK*1024);
    cvt_bf16<<<3072*1024/4/256, 256, 0, stream>>>(wq_w, wq_bf, 3072*1024);
    cvt_bf16<<<4096*512/4/256, 256, 0, stream>>>(wkvb_w, wkvb_bf, 4096*512);
    cvt_bf16<<<1024*2048/4/256, 256, 0, stream>>>(wo_w, wo_bf, 1024*2048);
    cvt_pad_kva<<<640*1024/4/256, 256, 0, stream>>>(wkva_w, wkva_b, wkva_bf, bias_pad);

    // 2) q = x @ wq^T + b   (8192 x 3072, K=1024)
    gemm_mfma<__hip_bfloat16, 0><<<dim3(3072/128, NTOK/128), 256, 0, stream>>>(
        xb, 1024, wq_bf, 1024, wq_b, q, 3072, 1024, nullptr);
    // 3) kv_a = x @ wkva^T + b  (8192 x 640 padded, K=1024)
    gemm_mfma<__hip_bfloat16, 0><<<dim3(640/128, NTOK/128), 256, 0, stream>>>(
        xb, 1024, wkva_bf, 1024, bias_pad, kvap, 640, 1024, nullptr);
    // 4) RoPE on q
    rope_q<<<NTOK, 512, 0, stream>>>(q, cs, sn);
    // 5) rmsnorm + rope-k
    rmsnorm_ropek<<<NTOK, 256, 0, stream>>>(kvap, kvn, kr, cs, sn);
    // 6) kv_b -> kn (k_nope) + vt (V transposed)
    gemm_mfma<__hip_bfloat16, 1><<<dim3(4096/128, NTOK/128), 256, 0, stream>>>(
        kvn, 512, wkvb_bf, 512, wkvb_b, kn, 0, 512, vt);
    // 7) barrier-free attention: one wave per 16 q-rows
    attn_mfma<<<dim3(T_/16, H_, B_), 64, 0, stream>>>(q, kn, kr, vt, attb);
    // 8) out = att @ wo^T + b  (8192 x 1024, K=2048)
    gemm_mfma<float, 0><<<dim3(1024/128, NTOK/128), 256, 0, stream>>>(
        attb, 2048, wo_bf, 2048, wo_b, out, 1024, 2048, nullptr);
}

// Round 8
// 724.297 us; speedup vs baseline: 1.7089x; 1.7089x over previous
//
#include <hip/hip_runtime.h>
#include <hip/hip_bf16.h>
#include <cmath>

// Problem constants
#define B_    4
#define T_    2048
#define DIM_  1024
#define H_    16
#define NOPE_ 128
#define ROPE_ 64
#define VDIM_ 128
#define KVR_  512
#define QKD_  192          // NOPE + ROPE
#define NTOK  (B_ * T_)    // 8192

static constexpr float SCALE_ = 0.07216878364870322f;  // 1/sqrt(192)

typedef __attribute__((ext_vector_type(8))) unsigned short ushort8_t;
typedef __bf16 v8bf __attribute__((ext_vector_type(8)));
typedef float  v4f  __attribute__((ext_vector_type(4)));

__device__ __forceinline__ float bf2f(unsigned short u) {
    return __uint_as_float(((unsigned int)u) << 16);
}
// round-to-nearest-even f32 -> bf16 bits (finite inputs)
__device__ __forceinline__ unsigned short f2bf(float f) {
    unsigned int u = __float_as_uint(f);
    u += 0x7FFFu + ((u >> 16) & 1u);
    return (unsigned short)(u >> 16);
}
__device__ __forceinline__ void store1(float* p, float v)          { *p = v; }
__device__ __forceinline__ void store1(__hip_bfloat16* p, float v) { *p = __float2bfloat16(v); }

// async global->LDS, 16B per lane. LDS dest = wave-uniform base + lane*16.
__device__ __forceinline__ void load_lds16(const void* g, void* l) {
    __builtin_amdgcn_global_load_lds(
        (const __attribute__((address_space(1))) void*)g,
        (__attribute__((address_space(3))) void*)l, 16, 0, 0);
}

// ---------------------------------------------------------------------------
// fp32 -> bf16 conversion (n % 4 == 0)
// ---------------------------------------------------------------------------
__global__ __launch_bounds__(256) void cvt_bf16(
    const float* __restrict__ s, __hip_bfloat16* __restrict__ d, int n)
{
    const int i = (blockIdx.x * 256 + threadIdx.x) * 4;
    if (i < n) {
        const float4 v = *(const float4*)(s + i);
        ushort4 o;
        o.x = f2bf(v.x); o.y = f2bf(v.y); o.z = f2bf(v.z); o.w = f2bf(v.w);
        *(ushort4*)((unsigned short*)d + i) = o;
    }
}

// wkv_a: (576,1024) fp32 -> (640,1024) bf16 zero-padded; bias 576 -> 640 fp32
__global__ __launch_bounds__(256) void cvt_pad_kva(
    const float* __restrict__ w, const float* __restrict__ b,
    __hip_bfloat16* __restrict__ wd, float* __restrict__ bd)
{
    const int gid = blockIdx.x * 256 + threadIdx.x;
    const int i = gid * 4;                     // over 640*1024
    if (i < 640 * 1024) {
        ushort4 o;
        if (i < 576 * 1024) {
            const float4 v = *(const float4*)(w + i);
            o.x = f2bf(v.x); o.y = f2bf(v.y); o.z = f2bf(v.z); o.w = f2bf(v.w);
        } else {
            o.x = o.y = o.z = o.w = 0;
        }
        *(ushort4*)((unsigned short*)wd + i) = o;
    }
    if (gid < 640) bd[gid] = (gid < 576) ? b[gid] : 0.0f;
}

// ---------------------------------------------------------------------------
// MFMA GEMM: C[m][n] = sum_k A[m][k]*W[n][k] + bias[n]. A,W bf16, acc fp32.
// Tiles 128x128xBK32, 4 waves (2x2 of 64x64), 16x16x32 MFMA.
// EPI=0: plain store to C. EPI=1: kv_b split epilogue (kn + vt transposed).
// ---------------------------------------------------------------------------
template <typename CT, int EPI>
__global__ __launch_bounds__(256) void gemm_mfma(
    const __hip_bfloat16* __restrict__ A, int lda,
    const __hip_bfloat16* __restrict__ W, int ldw,
    const float* __restrict__ bias,
    CT* __restrict__ C, int ldc, int K,
    __hip_bfloat16* __restrict__ vt)
{
    __shared__ unsigned short A_s[128 * 32];
    __shared__ unsigned short B_s[128 * 32];

    const int tid  = threadIdx.x;
    const int ln   = tid & 63;
    const int wv   = tid >> 6;
    const int l15  = ln & 15;
    const int quad = ln >> 4;
    const int wm   = wv & 1, wn = wv >> 1;
    const int n0 = blockIdx.x * 128, m0 = blockIdx.y * 128;

    v4f acc[4][4] = {};

    for (int k0 = 0; k0 < K; k0 += 32) {
        __syncthreads();
        #pragma unroll
        for (int it = 0; it < 2; ++it) {
            const int idx = it * 256 + wv * 64;   // wave-uniform LDS slot base
            const int li  = idx + ln;
            const int row = li >> 2, ch = li & 3;
            load_lds16(A + (size_t)(m0 + row) * lda + k0 + ch * 8, &A_s[idx * 8]);
            load_lds16(W + (size_t)(n0 + row) * ldw + k0 + ch * 8, &B_s[idx * 8]);
        }
        __syncthreads();

        v8bf af[4], bf_[4];
        #pragma unroll
        for (int i = 0; i < 4; ++i) {
            af[i]  = *(const v8bf*)&A_s[(wm * 64 + i * 16 + l15) * 32 + quad * 8];
            bf_[i] = *(const v8bf*)&B_s[(wn * 64 + i * 16 + l15) * 32 + quad * 8];
        }
        #pragma unroll
        for (int i = 0; i < 4; ++i)
            #pragma unroll
            for (int j = 0; j < 4; ++j)
                acc[i][j] = __builtin_amdgcn_mfma_f32_16x16x32_bf16(
                                af[i], bf_[j], acc[i][j], 0, 0, 0);
    }

    if (EPI == 0) {
        #pragma unroll
        for (int i = 0; i < 4; ++i) {
            const int mrow = m0 + wm * 64 + i * 16 + quad * 4;
            #pragma unroll
            for (int j = 0; j < 4; ++j) {
                const int ncol = n0 + wn * 64 + j * 16 + l15;
                const float bb = bias[ncol];
                #pragma unroll
                for (int r = 0; r < 4; ++r)
                    store1(C + (size_t)(mrow + r) * ldc + ncol, acc[i][j][r] + bb);
            }
        }
    } else {
        const int head = n0 >> 8;
        const bool is_v = (n0 & 128) != 0;
        #pragma unroll
        for (int i = 0; i < 4; ++i) {
            const int mrow = m0 + wm * 64 + i * 16 + quad * 4;
            #pragma unroll
            for (int j = 0; j < 4; ++j) {
                const int ncl = wn * 64 + j * 16 + l15;
                const float bb = bias[n0 + ncl];
                if (!is_v) {
                    __hip_bfloat16* kn = (__hip_bfloat16*)C;
                    #pragma unroll
                    for (int r = 0; r < 4; ++r)
                        kn[(size_t)(mrow + r) * 2048 + head * 128 + ncl] =
                            __float2bfloat16(acc[i][j][r] + bb);
                } else {
                    ushort4 pk;
                    pk.x = f2bf(acc[i][j][0] + bb);
                    pk.y = f2bf(acc[i][j][1] + bb);
                    pk.z = f2bf(acc[i][j][2] + bb);
                    pk.w = f2bf(acc[i][j][3] + bb);
                    *(ushort4*)((unsigned short*)vt +
                                ((size_t)head * 128 + ncl) * NTOK + mrow) = pk;
                }
            }
        }
    }
}

// ---------------------------------------------------------------------------
// RoPE on q's last 64 dims of each head. q: (NTOK, H*QKD) bf16.
// ---------------------------------------------------------------------------
__global__ __launch_bounds__(512) void rope_q(
    __hip_bfloat16* __restrict__ q,
    const float* __restrict__ cs,   // (T, 32)
    const float* __restrict__ sn)
{
    const int tok = blockIdx.x;
    const int tid = threadIdx.x;
    const int h = tid >> 5;
    const int i = tid & 31;
    const int t = tok & (T_ - 1);

    const float c = cs[t*32 + i];
    const float s = sn[t*32 + i];
    __hip_bfloat16* p = q + (size_t)tok * (H_*QKD_) + h*QKD_ + NOPE_ + 2*i;
    const float xr = __bfloat162float(p[0]);
    const float xi = __bfloat162float(p[1]);
    p[0] = __float2bfloat16(xr * c - xi * s);
    p[1] = __float2bfloat16(xr * s + xi * c);
}

// ---------------------------------------------------------------------------
// RMS-norm kv_a[:,0:512] -> kvn bf16; RoPE kv_a[:,512:576] -> kr bf16.
// ---------------------------------------------------------------------------
__global__ __launch_bounds__(256) void rmsnorm_ropek(
    const __hip_bfloat16* __restrict__ kva,
    __hip_bfloat16* __restrict__ kvn,
    __hip_bfloat16* __restrict__ kr,
    const float* __restrict__ cs,
    const float* __restrict__ sn)
{
    const int tok = blockIdx.x;
    const int tid = threadIdx.x;
    const __hip_bfloat16* row = kva + (size_t)tok * 640;

    const float x0 = __bfloat162float(row[tid]);
    const float x1 = __bfloat162float(row[tid + 256]);
    float ss = x0*x0 + x1*x1;
    #pragma unroll
    for (int off = 32; off >= 1; off >>= 1)
        ss += __shfl_down(ss, off);

    __shared__ float red[4];
    __shared__ float scale_sh;
    if ((tid & 63) == 0) red[tid >> 6] = ss;
    __syncthreads();
    if (tid == 0) {
        const float tot = red[0] + red[1] + red[2] + red[3];
        scale_sh = rsqrtf(tot * (1.0f/512.0f) + 1e-6f);
    }
    __syncthreads();
    const float sc = scale_sh;
    kvn[(size_t)tok*512 + tid]       = __float2bfloat16(x0 * sc);
    kvn[(size_t)tok*512 + tid + 256] = __float2bfloat16(x1 * sc);

    if (tid < 32) {
        const int t = tok & (T_ - 1);
        const float c = cs[t*32 + tid];
        const float s = sn[t*32 + tid];
        const float xr = __bfloat162float(row[KVR_ + 2*tid]);
        const float xi = __bfloat162float(row[KVR_ + 2*tid + 1]);
        kr[(size_t)tok*64 + 2*tid]     = __float2bfloat16(xr * c - xi * s);
        kr[(size_t)tok*64 + 2*tid + 1] = __float2bfloat16(xr * s + xi * c);
    }
}

// ---------------------------------------------------------------------------
// MFMA flash attention, BQ=128 / BK=64, 8 waves. Wave w owns q rows w*16..+15.
// K/V staged in FRAGMENT-ORDERED LDS (1 KB per MFMA fragment, read at
// base+lane*16 -> conflict-free ds_read_b128). Register-prefetch pipeline:
// tile kt+1's global loads (5 x 16B/thread) issue right after the barrier and
// are written to LDS only at the next tile -> full compute phase hides L2/HBM
// latency. LDS 58 KB -> 2 blocks/CU.
// Fragment blocks: f 0..23 = K (s=f>>2 of 6 k-chunks, t=f&3 of 4 col-tiles);
//                  f 24..39 = V (nt=(f-24)>>1, s2=(f-24)&1).
// ---------------------------------------------------------------------------
__device__ __forceinline__ void attn_stage_regs(
    v8bf* R,
    const __hip_bfloat16* __restrict__ kn,
    const __hip_bfloat16* __restrict__ kr,
    const __hip_bfloat16* __restrict__ vth,
    size_t tokb, int j0, int h, int wv, int ln, int quad)
{
    #pragma unroll
    for (int i = 0; i < 5; ++i) {
        const int f = wv * 5 + i;
        if (f < 24) {
            const int s = f >> 2, t = f & 3;
            const size_t row = tokb + j0 + t*16 + ln;
            R[i] = (s < 4)
                ? *(const v8bf*)(kn + row*2048 + h*128 + s*32 + quad*8)
                : *(const v8bf*)(kr + row*64 + (s-4)*32 + quad*8);
        } else {
            const int g2 = f - 24, nt = g2 >> 1, s2 = g2 & 1;
            R[i] = *(const v8bf*)(vth + (size_t)(nt*16 + ln)*NTOK
                                  + tokb + j0 + s2*32 + quad*8);
        }
    }
}

__global__ __launch_bounds__(512, 2) void attn_mfma(
    const __hip_bfloat16* __restrict__ q,
    const __hip_bfloat16* __restrict__ kn,
    const __hip_bfloat16* __restrict__ kr,
    const __hip_bfloat16* __restrict__ vt,
    __hip_bfloat16* __restrict__ att)
{
    __shared__ unsigned short KVf[40 * 512];     // 40 KB, fragment-ordered
    __shared__ unsigned short P_s[8][16 * 72];   // 18 KB, per-wave P

    const int tid  = threadIdx.x;
    const int lane = tid & 63;
    const int ln   = tid & 15;
    const int quad = (tid >> 4) & 3;
    const int wv   = tid >> 6;                   // 0..7

    const int qt = (int)(gridDim.x - 1) - (int)blockIdx.x;  // longest first
    const int h  = blockIdx.y, b = blockIdx.z;
    const int q0 = qt * 128;
    const size_t tokb = (size_t)b * T_;
    const __hip_bfloat16* vth = vt + (size_t)h * 128 * NTOK;

    // ---- Q fragments (A layout), pre-scaled ----
    v8bf qf[6];
    {
        const __hip_bfloat16* qrow =
            q + (tokb + q0 + wv*16 + ln) * (size_t)(H_*QKD_) + h*QKD_;
        #pragma unroll
        for (int s = 0; s < 6; ++s) {
            ushort8_t raw = *(const ushort8_t*)(qrow + s*32 + quad*8);
            ushort8_t sc;
            #pragma unroll
            for (int i = 0; i < 8; ++i)
                sc[i] = f2bf(bf2f(raw[i]) * SCALE_);
            qf[s] = __builtin_bit_cast(v8bf, sc);
        }
    }

    v4f O[8];
    #pragma unroll
    for (int nt = 0; nt < 8; ++nt) O[nt] = (v4f){0.f, 0.f, 0.f, 0.f};
    float m_r[4], l_r[4];
    #pragma unroll
    for (int r = 0; r < 4; ++r) { m_r[r] = -1e30f; l_r[r] = 0.0f; }

    const int qmin_w = q0 + wv*16;        // wave's lowest q row
    const int qmax_w = qmin_w + 15;       // wave's highest q row
    const int nkt = (q0 + 128) >> 6;

    // prefetch tile 0
    v8bf R[5];
    attn_stage_regs(R, kn, kr, vth, tokb, 0, h, wv, ln, quad);

    for (int kt = 0; kt < nkt; ++kt) {
        const int j0 = kt << 6;

        // regs -> LDS (compiler waits vmcnt for R; loads were issued a full
        // tile earlier, so the wait is ~free)
        #pragma unroll
        for (int i = 0; i < 5; ++i)
            *(v8bf*)&KVf[(wv*5 + i)*512 + lane*8] = R[i];
        __syncthreads();

        // issue next tile's loads (async; consumed next iteration)
        if (kt + 1 < nkt)
            attn_stage_regs(R, kn, kr, vth, tokb, j0 + 64, h, wv, ln, quad);

        if (j0 <= qmax_w) {   // wave-uniform skip of fully-masked tiles
            // ---- S = Q K^T ----
            v4f S[4];
            #pragma unroll
            for (int t = 0; t < 4; ++t) S[t] = (v4f){0.f, 0.f, 0.f, 0.f};
            #pragma unroll
            for (int s = 0; s < 6; ++s) {
                #pragma unroll
                for (int t = 0; t < 4; ++t) {
                    const v8bf kb = *(const v8bf*)&KVf[(s*4 + t)*512 + lane*8];
                    S[t] = __builtin_amdgcn_mfma_f32_16x16x32_bf16(qf[s], kb, S[t], 0, 0, 0);
                }
            }

            // ---- causal mask: needed whenever tile reaches past the wave's
            // LOWEST row (r7 bug: comparing against highest row under-masked) ----
            if (j0 + 63 > qmin_w) {
                #pragma unroll
                for (int t = 0; t < 4; ++t) {
                    const int kpos = j0 + t*16 + ln;
                    #pragma unroll
                    for (int r = 0; r < 4; ++r) {
                        const int qpos = qmin_w + quad*4 + r;
                        if (kpos > qpos) S[t][r] = -1e30f;
                    }
                }
            }

            // ---- online softmax ----
            float alpha[4];
            #pragma unroll
            for (int r = 0; r < 4; ++r) {
                float mx = fmaxf(fmaxf(S[0][r], S[1][r]), fmaxf(S[2][r], S[3][r]));
                #pragma unroll
                for (int off = 1; off < 16; off <<= 1)
                    mx = fmaxf(mx, __shfl_xor(mx, off));
                const float mn = fmaxf(m_r[r], mx);
                alpha[r] = __expf(m_r[r] - mn);
                m_r[r] = mn;
            }
            float rs[4] = {0.f, 0.f, 0.f, 0.f};
            #pragma unroll
            for (int t = 0; t < 4; ++t)
                #pragma unroll
                for (int r = 0; r < 4; ++r) {
                    const float pp = __expf(S[t][r] - m_r[r]);
                    S[t][r] = pp;
                    rs[r] += pp;
                }
            #pragma unroll
            for (int r = 0; r < 4; ++r) {
                #pragma unroll
                for (int off = 1; off < 16; off <<= 1)
                    rs[r] += __shfl_xor(rs[r], off);
                l_r[r] = l_r[r]*alpha[r] + rs[r];
            }

            // ---- P: C layout -> LDS -> A layout (wave-private) ----
            #pragma unroll
            for (int t = 0; t < 4; ++t)
                #pragma unroll
                for (int r = 0; r < 4; ++r)
                    P_s[wv][(quad*4 + r)*72 + t*16 + ln] = f2bf(S[t][r]);

            #pragma unroll
            for (int nt = 0; nt < 8; ++nt)
                #pragma unroll
                for (int r = 0; r < 4; ++r)
                    O[nt][r] *= alpha[r];

            // ---- O += P V ----
            #pragma unroll
            for (int s2 = 0; s2 < 2; ++s2) {
                const v8bf pa = *(const v8bf*)&P_s[wv][ln*72 + s2*32 + quad*8];
                #pragma unroll
                for (int nt = 0; nt < 8; ++nt) {
                    const v8bf vb = *(const v8bf*)&KVf[(24 + nt*2 + s2)*512 + lane*8];
                    O[nt] = __builtin_amdgcn_mfma_f32_16x16x32_bf16(pa, vb, O[nt], 0, 0, 0);
                }
            }
        }
        __syncthreads();
    }

    // ---- epilogue ----
    __hip_bfloat16* obase = att + (tokb + q0 + wv*16) * (size_t)(H_*VDIM_) + h*VDIM_;
    #pragma unroll
    for (int r = 0; r < 4; ++r) {
        const float inv = 1.0f / l_r[r];
        __hip_bfloat16* orow = obase + (size_t)(quad*4 + r) * (H_*VDIM_);
        #pragma unroll
        for (int nt = 0; nt < 8; ++nt)
            orow[nt*16 + ln] = __float2bfloat16(O[nt][r] * inv);
    }
}

// Diagnostic fallback
__global__ void fill_zero(float* p, int n) {
    int i = blockIdx.x * 256 + threadIdx.x;
    if (i < n) p[i] = 0.0f;
}

// ---------------------------------------------------------------------------
extern "C" void kernel_launch(void* const* d_in, const int* in_sizes, int n_in,
                              void* d_out, int out_size, void* d_ws, size_t ws_size,
                              hipStream_t stream)
{
    const float* x      = (const float*)d_in[0];
    const float* wq_w   = (const float*)d_in[1];
    const float* wq_b   = (const float*)d_in[2];
    const float* wkva_w = (const float*)d_in[3];
    const float* wkva_b = (const float*)d_in[4];
    const float* wkvb_w = (const float*)d_in[5];
    const float* wkvb_b = (const float*)d_in[6];
    const float* wo_w   = (const float*)d_in[7];
    const float* wo_b   = (const float*)d_in[8];
    const float* cs     = (const float*)d_in[9];
    const float* sn     = (const float*)d_in[10];

    const size_t q_b    = (size_t)NTOK * 3072 * 2;
    const size_t kn_b   = (size_t)NTOK * 2048 * 2;
    const size_t vt_b   = (size_t)H_ * 128 * NTOK * 2;
    const size_t xb_b   = (size_t)NTOK * 1024 * 2;
    const size_t kvap_b = (size_t)NTOK * 640 * 2;
    const size_t kvn_b  = (size_t)NTOK * 512 * 2;
    const size_t wq_b_b = (size_t)3072 * 1024 * 2;
    const size_t wkva_b_b = (size_t)640 * 1024 * 2;
    const size_t wkvb_b_b = (size_t)4096 * 512 * 2;
    const size_t wo_b_b   = (size_t)1024 * 2048 * 2;
    const size_t bias_b   = 4096;
    const size_t need = q_b + kn_b + vt_b + xb_b + kvap_b + kvn_b +
                        wq_b_b + wkva_b_b + wkvb_b_b + wo_b_b + bias_b;

    if (ws_size < need) {
        fill_zero<<<(out_size + 255) / 256, 256, 0, stream>>>((float*)d_out, out_size);
        return;
    }

    char* p = (char*)d_ws;
    __hip_bfloat16* q    = (__hip_bfloat16*)p;             p += q_b;
    __hip_bfloat16* kn   = (__hip_bfloat16*)p;             p += kn_b;
    __hip_bfloat16* vt   = (__hip_bfloat16*)p;             p += vt_b;
    char*           dynr = p;
    __hip_bfloat16* xb   = (__hip_bfloat16*)p;             p += xb_b;
    __hip_bfloat16* kvap = (__hip_bfloat16*)p;             p += kvap_b;
    __hip_bfloat16* kvn  = (__hip_bfloat16*)p;             p += kvn_b;
    __hip_bfloat16* wq_bf = (__hip_bfloat16*)p;
    __hip_bfloat16* kr    = (__hip_bfloat16*)p;            p += wq_b_b;
    __hip_bfloat16* wkva_bf = (__hip_bfloat16*)p;          p += wkva_b_b;
    __hip_bfloat16* wkvb_bf = (__hip_bfloat16*)p;          p += wkvb_b_b;
    __hip_bfloat16* wo_bf   = (__hip_bfloat16*)p;          p += wo_b_b;
    float*          bias_pad = (float*)p;
    __hip_bfloat16* attb = (__hip_bfloat16*)dynr;
    float*          out  = (float*)d_out;

    // 1) conversions
    cvt_bf16<<<NTOK*1024/4/256, 256, 0, stream>>>(x, xb, NTOK*1024);
    cvt_bf16<<<3072*1024/4/256, 256, 0, stream>>>(wq_w, wq_bf, 3072*1024);
    cvt_bf16<<<4096*512/4/256, 256, 0, stream>>>(wkvb_w, wkvb_bf, 4096*512);
    cvt_bf16<<<1024*2048/4/256, 256, 0, stream>>>(wo_w, wo_bf, 1024*2048);
    cvt_pad_kva<<<640*1024/4/256, 256, 0, stream>>>(wkva_w, wkva_b, wkva_bf, bias_pad);

    // 2) q = x @ wq^T + b   (8192 x 3072, K=1024)
    gemm_mfma<__hip_bfloat16, 0><<<dim3(3072/128, NTOK/128), 256, 0, stream>>>(
        xb, 1024, wq_bf, 1024, wq_b, q, 3072, 1024, nullptr);
    // 3) kv_a = x @ wkva^T + b  (8192 x 640 padded, K=1024)
    gemm_mfma<__hip_bfloat16, 0><<<dim3(640/128, NTOK/128), 256, 0, stream>>>(
        xb, 1024, wkva_bf, 1024, bias_pad, kvap, 640, 1024, nullptr);
    // 4) RoPE on q
    rope_q<<<NTOK, 512, 0, stream>>>(q, cs, sn);
    // 5) rmsnorm + rope-k
    rmsnorm_ropek<<<NTOK, 256, 0, stream>>>(kvap, kvn, kr, cs, sn);
    // 6) kv_b -> kn (k_nope) + vt (V transposed)
    gemm_mfma<__hip_bfloat16, 1><<<dim3(4096/128, NTOK/128), 256, 0, stream>>>(
        kvn, 512, wkvb_bf, 512, wkvb_b, kn, 0, 512, vt);
    // 7) attention: BQ=128, 8 waves, reg-prefetch pipeline
    attn_mfma<<<dim3(T_/128, H_, B_), 512, 0, stream>>>(q, kn, kr, vt, attb);
    // 8) out = att @ wo^T + b  (8192 x 1024, K=2048)
    gemm_mfma<float, 0><<<dim3(1024/128, NTOK/128), 256, 0, stream>>>(
        attb, 2048, wo_bf, 2048, wo_b, out, 1024, 2048, nullptr);
}

// Round 9
// 711.079 us; speedup vs baseline: 1.7406x; 1.0186x over previous
//
#include <hip/hip_runtime.h>
#include <hip/hip_bf16.h>
#include <cmath>

// Problem constants
#define B_    4
#define T_    2048
#define DIM_  1024
#define H_    16
#define NOPE_ 128
#define ROPE_ 64
#define VDIM_ 128
#define KVR_  512
#define QKD_  192          // NOPE + ROPE
#define NTOK  (B_ * T_)    // 8192

static constexpr float SCALE_ = 0.07216878364870322f;  // 1/sqrt(192)

typedef __attribute__((ext_vector_type(8))) unsigned short ushort8_t;
typedef __bf16 v8bf __attribute__((ext_vector_type(8)));
typedef float  v4f  __attribute__((ext_vector_type(4)));

__device__ __forceinline__ float bf2f(unsigned short u) {
    return __uint_as_float(((unsigned int)u) << 16);
}
// round-to-nearest-even f32 -> bf16 bits (finite inputs)
__device__ __forceinline__ unsigned short f2bf(float f) {
    unsigned int u = __float_as_uint(f);
    u += 0x7FFFu + ((u >> 16) & 1u);
    return (unsigned short)(u >> 16);
}
__device__ __forceinline__ void store1(float* p, float v)          { *p = v; }
__device__ __forceinline__ void store1(__hip_bfloat16* p, float v) { *p = __float2bfloat16(v); }

// async global->LDS, 16B per lane. LDS dest = wave-uniform base + lane*16.
__device__ __forceinline__ void load_lds16(const void* g, void* l) {
    __builtin_amdgcn_global_load_lds(
        (const __attribute__((address_space(1))) void*)g,
        (__attribute__((address_space(3))) void*)l, 16, 0, 0);
}

// ---------------------------------------------------------------------------
// fp32 -> bf16 conversion (n % 4 == 0)
// ---------------------------------------------------------------------------
__global__ __launch_bounds__(256) void cvt_bf16(
    const float* __restrict__ s, __hip_bfloat16* __restrict__ d, int n)
{
    const int i = (blockIdx.x * 256 + threadIdx.x) * 4;
    if (i < n) {
        const float4 v = *(const float4*)(s + i);
        ushort4 o;
        o.x = f2bf(v.x); o.y = f2bf(v.y); o.z = f2bf(v.z); o.w = f2bf(v.w);
        *(ushort4*)((unsigned short*)d + i) = o;
    }
}

// wkv_a: (576,1024) fp32 -> (640,1024) bf16 zero-padded; bias 576 -> 640 fp32
__global__ __launch_bounds__(256) void cvt_pad_kva(
    const float* __restrict__ w, const float* __restrict__ b,
    __hip_bfloat16* __restrict__ wd, float* __restrict__ bd)
{
    const int gid = blockIdx.x * 256 + threadIdx.x;
    const int i = gid * 4;                     // over 640*1024
    if (i < 640 * 1024) {
        ushort4 o;
        if (i < 576 * 1024) {
            const float4 v = *(const float4*)(w + i);
            o.x = f2bf(v.x); o.y = f2bf(v.y); o.z = f2bf(v.z); o.w = f2bf(v.w);
        } else {
            o.x = o.y = o.z = o.w = 0;
        }
        *(ushort4*)((unsigned short*)wd + i) = o;
    }
    if (gid < 640) bd[gid] = (gid < 576) ? b[gid] : 0.0f;
}

// ---------------------------------------------------------------------------
// MFMA GEMM: C[m][n] = sum_k A[m][k]*W[n][k] + bias[n]. A,W bf16, acc fp32.
// Tiles 128x128xBK32, 4 waves (2x2 of 64x64), 16x16x32 MFMA.
// EPI=0: plain store to C. EPI=1: kv_b split epilogue (kn + vt transposed).
// ---------------------------------------------------------------------------
template <typename CT, int EPI>
__global__ __launch_bounds__(256) void gemm_mfma(
    const __hip_bfloat16* __restrict__ A, int lda,
    const __hip_bfloat16* __restrict__ W, int ldw,
    const float* __restrict__ bias,
    CT* __restrict__ C, int ldc, int K,
    __hip_bfloat16* __restrict__ vt)
{
    __shared__ unsigned short A_s[128 * 32];
    __shared__ unsigned short B_s[128 * 32];

    const int tid  = threadIdx.x;
    const int ln   = tid & 63;
    const int wv   = tid >> 6;
    const int l15  = ln & 15;
    const int quad = ln >> 4;
    const int wm   = wv & 1, wn = wv >> 1;
    const int n0 = blockIdx.x * 128, m0 = blockIdx.y * 128;

    v4f acc[4][4] = {};

    for (int k0 = 0; k0 < K; k0 += 32) {
        __syncthreads();
        #pragma unroll
        for (int it = 0; it < 2; ++it) {
            const int idx = it * 256 + wv * 64;   // wave-uniform LDS slot base
            const int li  = idx + ln;
            const int row = li >> 2, ch = li & 3;
            load_lds16(A + (size_t)(m0 + row) * lda + k0 + ch * 8, &A_s[idx * 8]);
            load_lds16(W + (size_t)(n0 + row) * ldw + k0 + ch * 8, &B_s[idx * 8]);
        }
        __syncthreads();

        v8bf af[4], bf_[4];
        #pragma unroll
        for (int i = 0; i < 4; ++i) {
            af[i]  = *(const v8bf*)&A_s[(wm * 64 + i * 16 + l15) * 32 + quad * 8];
            bf_[i] = *(const v8bf*)&B_s[(wn * 64 + i * 16 + l15) * 32 + quad * 8];
        }
        #pragma unroll
        for (int i = 0; i < 4; ++i)
            #pragma unroll
            for (int j = 0; j < 4; ++j)
                acc[i][j] = __builtin_amdgcn_mfma_f32_16x16x32_bf16(
                                af[i], bf_[j], acc[i][j], 0, 0, 0);
    }

    if (EPI == 0) {
        #pragma unroll
        for (int i = 0; i < 4; ++i) {
            const int mrow = m0 + wm * 64 + i * 16 + quad * 4;
            #pragma unroll
            for (int j = 0; j < 4; ++j) {
                const int ncol = n0 + wn * 64 + j * 16 + l15;
                const float bb = bias[ncol];
                #pragma unroll
                for (int r = 0; r < 4; ++r)
                    store1(C + (size_t)(mrow + r) * ldc + ncol, acc[i][j][r] + bb);
            }
        }
    } else {
        const int head = n0 >> 8;
        const bool is_v = (n0 & 128) != 0;
        #pragma unroll
        for (int i = 0; i < 4; ++i) {
            const int mrow = m0 + wm * 64 + i * 16 + quad * 4;
            #pragma unroll
            for (int j = 0; j < 4; ++j) {
                const int ncl = wn * 64 + j * 16 + l15;
                const float bb = bias[n0 + ncl];
                if (!is_v) {
                    __hip_bfloat16* kn = (__hip_bfloat16*)C;
                    #pragma unroll
                    for (int r = 0; r < 4; ++r)
                        kn[(size_t)(mrow + r) * 2048 + head * 128 + ncl] =
                            __float2bfloat16(acc[i][j][r] + bb);
                } else {
                    ushort4 pk;
                    pk.x = f2bf(acc[i][j][0] + bb);
                    pk.y = f2bf(acc[i][j][1] + bb);
                    pk.z = f2bf(acc[i][j][2] + bb);
                    pk.w = f2bf(acc[i][j][3] + bb);
                    *(ushort4*)((unsigned short*)vt +
                                ((size_t)head * 128 + ncl) * NTOK + mrow) = pk;
                }
            }
        }
    }
}

// ---------------------------------------------------------------------------
// RMS-norm kv_a[:,0:512] -> kvn bf16; RoPE kv_a[:,512:576] -> kr bf16.
// ---------------------------------------------------------------------------
__global__ __launch_bounds__(256) void rmsnorm_ropek(
    const __hip_bfloat16* __restrict__ kva,
    __hip_bfloat16* __restrict__ kvn,
    __hip_bfloat16* __restrict__ kr,
    const float* __restrict__ cs,
    const float* __restrict__ sn)
{
    const int tok = blockIdx.x;
    const int tid = threadIdx.x;
    const __hip_bfloat16* row = kva + (size_t)tok * 640;

    const float x0 = __bfloat162float(row[tid]);
    const float x1 = __bfloat162float(row[tid + 256]);
    float ss = x0*x0 + x1*x1;
    #pragma unroll
    for (int off = 32; off >= 1; off >>= 1)
        ss += __shfl_down(ss, off);

    __shared__ float red[4];
    __shared__ float scale_sh;
    if ((tid & 63) == 0) red[tid >> 6] = ss;
    __syncthreads();
    if (tid == 0) {
        const float tot = red[0] + red[1] + red[2] + red[3];
        scale_sh = rsqrtf(tot * (1.0f/512.0f) + 1e-6f);
    }
    __syncthreads();
    const float sc = scale_sh;
    kvn[(size_t)tok*512 + tid]       = __float2bfloat16(x0 * sc);
    kvn[(size_t)tok*512 + tid + 256] = __float2bfloat16(x1 * sc);

    if (tid < 32) {
        const int t = tok & (T_ - 1);
        const float c = cs[t*32 + tid];
        const float s = sn[t*32 + tid];
        const float xr = __bfloat162float(row[KVR_ + 2*tid]);
        const float xi = __bfloat162float(row[KVR_ + 2*tid + 1]);
        kr[(size_t)tok*64 + 2*tid]     = __float2bfloat16(xr * c - xi * s);
        kr[(size_t)tok*64 + 2*tid + 1] = __float2bfloat16(xr * s + xi * c);
    }
}

// ---------------------------------------------------------------------------
// MFMA flash attention, BQ=256 / BK=64, 8 waves, TWO q-strips per wave
// (rows q0+wv*16 and q0+128+wv*16): each K/V B-fragment read from LDS once
// feeds 2 MFMAs -> LDS reads per FLOP halve vs r8. RoPE on q is fused into
// the Q-load (q elements are read exactly once across the attention grid).
// Fragment-ordered LDS staging + register-prefetch pipeline as in r8.
// Fragment blocks: f 0..23 = K (s=f>>2, t=f&3); f 24..39 = V (nt,s2).
// ---------------------------------------------------------------------------
__device__ __forceinline__ void attn_stage_regs(
    v8bf* R,
    const __hip_bfloat16* __restrict__ kn,
    const __hip_bfloat16* __restrict__ kr,
    const __hip_bfloat16* __restrict__ vth,
    size_t tokb, int j0, int h, int wv, int ln, int quad)
{
    #pragma unroll
    for (int i = 0; i < 5; ++i) {
        const int f = wv * 5 + i;
        if (f < 24) {
            const int s = f >> 2, t = f & 3;
            const size_t row = tokb + j0 + t*16 + ln;
            R[i] = (s < 4)
                ? *(const v8bf*)(kn + row*2048 + h*128 + s*32 + quad*8)
                : *(const v8bf*)(kr + row*64 + (s-4)*32 + quad*8);
        } else {
            const int g2 = f - 24, nt = g2 >> 1, s2 = g2 & 1;
            R[i] = *(const v8bf*)(vth + (size_t)(nt*16 + ln)*NTOK
                                  + tokb + j0 + s2*32 + quad*8);
        }
    }
}

__global__ __launch_bounds__(512, 2) void attn_mfma(
    const __hip_bfloat16* __restrict__ q,
    const __hip_bfloat16* __restrict__ kn,
    const __hip_bfloat16* __restrict__ kr,
    const __hip_bfloat16* __restrict__ vt,
    const float* __restrict__ cs,
    const float* __restrict__ sn,
    __hip_bfloat16* __restrict__ att)
{
    __shared__ unsigned short KVf[40 * 512];        // 40 KB, fragment-ordered
    __shared__ unsigned short P_s[8][2][16 * 72];   // 36 KB, per-wave/strip P

    const int tid  = threadIdx.x;
    const int lane = tid & 63;
    const int ln   = tid & 15;
    const int quad = (tid >> 4) & 3;
    const int wv   = tid >> 6;                      // 0..7

    const int qt = (int)(gridDim.x - 1) - (int)blockIdx.x;  // longest first
    const int h  = blockIdx.y, b = blockIdx.z;
    const int q0 = qt * 256;
    const size_t tokb = (size_t)b * T_;
    const __hip_bfloat16* vth = vt + (size_t)h * 128 * NTOK;

    // ---- Q fragments for both strips (A layout), fused RoPE + scale ----
    v8bf qf[2][6];
    #pragma unroll
    for (int st = 0; st < 2; ++st) {
        const int trow = q0 + st*128 + wv*16 + ln;   // position in sequence
        const __hip_bfloat16* qrow =
            q + (tokb + trow) * (size_t)(H_*QKD_) + h*QKD_;
        #pragma unroll
        for (int s = 0; s < 6; ++s) {
            ushort8_t raw = *(const ushort8_t*)(qrow + s*32 + quad*8);
            ushort8_t o;
            if (s < 4) {
                #pragma unroll
                for (int i = 0; i < 8; ++i)
                    o[i] = f2bf(bf2f(raw[i]) * SCALE_);
            } else {
                #pragma unroll
                for (int p2 = 0; p2 < 4; ++p2) {
                    const int fi = (s-4)*16 + quad*4 + p2;   // freq index 0..31
                    const float c  = cs[trow*32 + fi];
                    const float sv = sn[trow*32 + fi];
                    const float xr = bf2f(raw[p2*2]);
                    const float xi = bf2f(raw[p2*2+1]);
                    o[p2*2]   = f2bf((xr*c - xi*sv) * SCALE_);
                    o[p2*2+1] = f2bf((xr*sv + xi*c) * SCALE_);
                }
            }
            qf[st][s] = __builtin_bit_cast(v8bf, o);
        }
    }

    v4f O[2][8];
    #pragma unroll
    for (int st = 0; st < 2; ++st)
        #pragma unroll
        for (int nt = 0; nt < 8; ++nt) O[st][nt] = (v4f){0.f, 0.f, 0.f, 0.f};
    float m_r[2][4], l_r[2][4];
    #pragma unroll
    for (int st = 0; st < 2; ++st)
        #pragma unroll
        for (int r = 0; r < 4; ++r) { m_r[st][r] = -1e30f; l_r[st][r] = 0.0f; }

    const int qmin0 = q0 + wv*16;
    const int qmin1 = q0 + 128 + wv*16;
    const int nkt = (q0 + 256) >> 6;

    // prefetch tile 0
    v8bf R[5];
    attn_stage_regs(R, kn, kr, vth, tokb, 0, h, wv, ln, quad);

    for (int kt = 0; kt < nkt; ++kt) {
        const int j0 = kt << 6;

        #pragma unroll
        for (int i = 0; i < 5; ++i)
            *(v8bf*)&KVf[(wv*5 + i)*512 + lane*8] = R[i];
        __syncthreads();

        if (kt + 1 < nkt)
            attn_stage_regs(R, kn, kr, vth, tokb, j0 + 64, h, wv, ln, quad);

        const bool act0 = (j0 <= qmin0 + 15);   // wave-uniform
        const bool act1 = (j0 <= qmin1 + 15);

        if (act1) {
            // ---- S = Q K^T: each kb fragment feeds 1 or 2 strips ----
            v4f S[2][4];
            #pragma unroll
            for (int st = 0; st < 2; ++st)
                #pragma unroll
                for (int t = 0; t < 4; ++t) S[st][t] = (v4f){0.f, 0.f, 0.f, 0.f};
            if (act0) {
                #pragma unroll
                for (int s = 0; s < 6; ++s)
                    #pragma unroll
                    for (int t = 0; t < 4; ++t) {
                        const v8bf kb = *(const v8bf*)&KVf[(s*4 + t)*512 + lane*8];
                        S[0][t] = __builtin_amdgcn_mfma_f32_16x16x32_bf16(qf[0][s], kb, S[0][t], 0, 0, 0);
                        S[1][t] = __builtin_amdgcn_mfma_f32_16x16x32_bf16(qf[1][s], kb, S[1][t], 0, 0, 0);
                    }
            } else {
                #pragma unroll
                for (int s = 0; s < 6; ++s)
                    #pragma unroll
                    for (int t = 0; t < 4; ++t) {
                        const v8bf kb = *(const v8bf*)&KVf[(s*4 + t)*512 + lane*8];
                        S[1][t] = __builtin_amdgcn_mfma_f32_16x16x32_bf16(qf[1][s], kb, S[1][t], 0, 0, 0);
                    }
            }

            // ---- per-strip mask + online softmax + P write ----
            float alpha[2][4];
            #pragma unroll
            for (int st = 0; st < 2; ++st) {
                if (st == 0 && !act0) continue;
                const int qmin = (st == 0) ? qmin0 : qmin1;
                if (j0 + 63 > qmin) {
                    #pragma unroll
                    for (int t = 0; t < 4; ++t) {
                        const int kpos = j0 + t*16 + ln;
                        #pragma unroll
                        for (int r = 0; r < 4; ++r)
                            if (kpos > qmin + quad*4 + r) S[st][t][r] = -1e30f;
                    }
                }
                #pragma unroll
                for (int r = 0; r < 4; ++r) {
                    float mx = fmaxf(fmaxf(S[st][0][r], S[st][1][r]),
                                     fmaxf(S[st][2][r], S[st][3][r]));
                    #pragma unroll
                    for (int off = 1; off < 16; off <<= 1)
                        mx = fmaxf(mx, __shfl_xor(mx, off));
                    const float mn = fmaxf(m_r[st][r], mx);
                    alpha[st][r] = __expf(m_r[st][r] - mn);
                    m_r[st][r] = mn;
                }
                float rs[4] = {0.f, 0.f, 0.f, 0.f};
                #pragma unroll
                for (int t = 0; t < 4; ++t)
                    #pragma unroll
                    for (int r = 0; r < 4; ++r) {
                        const float pp = __expf(S[st][t][r] - m_r[st][r]);
                        S[st][t][r] = pp;
                        rs[r] += pp;
                    }
                #pragma unroll
                for (int r = 0; r < 4; ++r) {
                    #pragma unroll
                    for (int off = 1; off < 16; off <<= 1)
                        rs[r] += __shfl_xor(rs[r], off);
                    l_r[st][r] = l_r[st][r]*alpha[st][r] + rs[r];
                }
                #pragma unroll
                for (int t = 0; t < 4; ++t)
                    #pragma unroll
                    for (int r = 0; r < 4; ++r)
                        P_s[wv][st][(quad*4 + r)*72 + t*16 + ln] = f2bf(S[st][t][r]);
                #pragma unroll
                for (int nt = 0; nt < 8; ++nt)
                    #pragma unroll
                    for (int r = 0; r < 4; ++r)
                        O[st][nt][r] *= alpha[st][r];
            }

            // ---- O += P V: each vb fragment feeds 1 or 2 strips ----
            #pragma unroll
            for (int s2 = 0; s2 < 2; ++s2) {
                const v8bf pa1 = *(const v8bf*)&P_s[wv][1][ln*72 + s2*32 + quad*8];
                if (act0) {
                    const v8bf pa0 = *(const v8bf*)&P_s[wv][0][ln*72 + s2*32 + quad*8];
                    #pragma unroll
                    for (int nt = 0; nt < 8; ++nt) {
                        const v8bf vb = *(const v8bf*)&KVf[(24 + nt*2 + s2)*512 + lane*8];
                        O[0][nt] = __builtin_amdgcn_mfma_f32_16x16x32_bf16(pa0, vb, O[0][nt], 0, 0, 0);
                        O[1][nt] = __builtin_amdgcn_mfma_f32_16x16x32_bf16(pa1, vb, O[1][nt], 0, 0, 0);
                    }
                } else {
                    #pragma unroll
                    for (int nt = 0; nt < 8; ++nt) {
                        const v8bf vb = *(const v8bf*)&KVf[(24 + nt*2 + s2)*512 + lane*8];
                        O[1][nt] = __builtin_amdgcn_mfma_f32_16x16x32_bf16(pa1, vb, O[1][nt], 0, 0, 0);
                    }
                }
            }
        }
        __syncthreads();
    }

    // ---- epilogue: both strips ----
    #pragma unroll
    for (int st = 0; st < 2; ++st) {
        __hip_bfloat16* obase =
            att + (tokb + q0 + st*128 + wv*16) * (size_t)(H_*VDIM_) + h*VDIM_;
        #pragma unroll
        for (int r = 0; r < 4; ++r) {
            const float inv = 1.0f / l_r[st][r];
            __hip_bfloat16* orow = obase + (size_t)(quad*4 + r) * (H_*VDIM_);
            #pragma unroll
            for (int nt = 0; nt < 8; ++nt)
                orow[nt*16 + ln] = __float2bfloat16(O[st][nt][r] * inv);
        }
    }
}

// Diagnostic fallback
__global__ void fill_zero(float* p, int n) {
    int i = blockIdx.x * 256 + threadIdx.x;
    if (i < n) p[i] = 0.0f;
}

// ---------------------------------------------------------------------------
extern "C" void kernel_launch(void* const* d_in, const int* in_sizes, int n_in,
                              void* d_out, int out_size, void* d_ws, size_t ws_size,
                              hipStream_t stream)
{
    const float* x      = (const float*)d_in[0];
    const float* wq_w   = (const float*)d_in[1];
    const float* wq_b   = (const float*)d_in[2];
    const float* wkva_w = (const float*)d_in[3];
    const float* wkva_b = (const float*)d_in[4];
    const float* wkvb_w = (const float*)d_in[5];
    const float* wkvb_b = (const float*)d_in[6];
    const float* wo_w   = (const float*)d_in[7];
    const float* wo_b   = (const float*)d_in[8];
    const float* cs     = (const float*)d_in[9];
    const float* sn     = (const float*)d_in[10];

    const size_t q_b    = (size_t)NTOK * 3072 * 2;
    const size_t kn_b   = (size_t)NTOK * 2048 * 2;
    const size_t vt_b   = (size_t)H_ * 128 * NTOK * 2;
    const size_t xb_b   = (size_t)NTOK * 1024 * 2;
    const size_t kvap_b = (size_t)NTOK * 640 * 2;
    const size_t kvn_b  = (size_t)NTOK * 512 * 2;
    const size_t wq_b_b = (size_t)3072 * 1024 * 2;
    const size_t wkva_b_b = (size_t)640 * 1024 * 2;
    const size_t wkvb_b_b = (size_t)4096 * 512 * 2;
    const size_t wo_b_b   = (size_t)1024 * 2048 * 2;
    const size_t bias_b   = 4096;
    const size_t need = q_b + kn_b + vt_b + xb_b + kvap_b + kvn_b +
                        wq_b_b + wkva_b_b + wkvb_b_b + wo_b_b + bias_b;

    if (ws_size < need) {
        fill_zero<<<(out_size + 255) / 256, 256, 0, stream>>>((float*)d_out, out_size);
        return;
    }

    char* p = (char*)d_ws;
    __hip_bfloat16* q    = (__hip_bfloat16*)p;             p += q_b;
    __hip_bfloat16* kn   = (__hip_bfloat16*)p;             p += kn_b;
    __hip_bfloat16* vt   = (__hip_bfloat16*)p;             p += vt_b;
    char*           dynr = p;
    __hip_bfloat16* xb   = (__hip_bfloat16*)p;             p += xb_b;
    __hip_bfloat16* kvap = (__hip_bfloat16*)p;             p += kvap_b;
    __hip_bfloat16* kvn  = (__hip_bfloat16*)p;             p += kvn_b;
    __hip_bfloat16* wq_bf = (__hip_bfloat16*)p;
    __hip_bfloat16* kr    = (__hip_bfloat16*)p;            p += wq_b_b;
    __hip_bfloat16* wkva_bf = (__hip_bfloat16*)p;          p += wkva_b_b;
    __hip_bfloat16* wkvb_bf = (__hip_bfloat16*)p;          p += wkvb_b_b;
    __hip_bfloat16* wo_bf   = (__hip_bfloat16*)p;          p += wo_b_b;
    float*          bias_pad = (float*)p;
    __hip_bfloat16* attb = (__hip_bfloat16*)dynr;
    float*          out  = (float*)d_out;

    // 1) conversions
    cvt_bf16<<<NTOK*1024/4/256, 256, 0, stream>>>(x, xb, NTOK*1024);
    cvt_bf16<<<3072*1024/4/256, 256, 0, stream>>>(wq_w, wq_bf, 3072*1024);
    cvt_bf16<<<4096*512/4/256, 256, 0, stream>>>(wkvb_w, wkvb_bf, 4096*512);
    cvt_bf16<<<1024*2048/4/256, 256, 0, stream>>>(wo_w, wo_bf, 1024*2048);
    cvt_pad_kva<<<640*1024/4/256, 256, 0, stream>>>(wkva_w, wkva_b, wkva_bf, bias_pad);

    // 2) q = x @ wq^T + b   (8192 x 3072, K=1024)  [q-RoPE now fused in attn]
    gemm_mfma<__hip_bfloat16, 0><<<dim3(3072/128, NTOK/128), 256, 0, stream>>>(
        xb, 1024, wq_bf, 1024, wq_b, q, 3072, 1024, nullptr);
    // 3) kv_a = x @ wkva^T + b  (8192 x 640 padded, K=1024)
    gemm_mfma<__hip_bfloat16, 0><<<dim3(640/128, NTOK/128), 256, 0, stream>>>(
        xb, 1024, wkva_bf, 1024, bias_pad, kvap, 640, 1024, nullptr);
    // 4) rmsnorm + rope-k
    rmsnorm_ropek<<<NTOK, 256, 0, stream>>>(kvap, kvn, kr, cs, sn);
    // 5) kv_b -> kn (k_nope) + vt (V transposed)
    gemm_mfma<__hip_bfloat16, 1><<<dim3(4096/128, NTOK/128), 256, 0, stream>>>(
        kvn, 512, wkvb_bf, 512, wkvb_b, kn, 0, 512, vt);
    // 6) attention: BQ=256, 8 waves x 2 strips, fused q-RoPE
    attn_mfma<<<dim3(T_/256, H_, B_), 512, 0, stream>>>(q, kn, kr, vt, cs, sn, attb);
    // 7) out = att @ wo^T + b  (8192 x 1024, K=2048)
    gemm_mfma<float, 0><<<dim3(1024/128, NTOK/128), 256, 0, stream>>>(
        attb, 2048, wo_bf, 2048, wo_b, out, 1024, 2048, nullptr);
}